// Round 1
// baseline (690.926 us; speedup 1.0000x reference)
//
#include <hip/hip_runtime.h>
#include <stdint.h>
#include <stddef.h>

// ---------------------------------------------------------------------------
// EncoderImageAggr: fused bf16-MFMA pipeline for MI355X (gfx950)
// B=256 L=64 IMG_DIM=2048 D=1024 H=8 DH=128, all GEMM weights are (N,K) so
// every GEMM is C = A @ B^T ("gemm_bt", the verified m97 structure).
// ---------------------------------------------------------------------------

typedef short s16x8 __attribute__((ext_vector_type(8)));
typedef short s16x4 __attribute__((ext_vector_type(4)));
typedef float f32x4 __attribute__((ext_vector_type(4)));

#define LN_EPSF 1e-5f
#define BN_EPSF 1e-5f

__device__ __forceinline__ short f2bf(float f) {
  union { float f; uint32_t u; } x; x.f = f;
  uint32_t r = x.u + 0x7fffu + ((x.u >> 16) & 1u);   // RNE
  return (short)(r >> 16);
}

typedef const __attribute__((address_space(1))) short glb_s16_t;
typedef __attribute__((address_space(3))) short lds_s16_t;

// async global->LDS, 16B per lane, LDS dest = uniform base + lane*16
__device__ __forceinline__ void stage16(const short* g, short* l) {
  __builtin_amdgcn_global_load_lds((glb_s16_t*)g, (lds_s16_t*)l, 16, 0, 0);
}

// ---------------------------------------------------------------------------
// fp32 -> bf16 convert
// ---------------------------------------------------------------------------
__global__ __launch_bounds__(256)
void cvt_kernel(const float* __restrict__ in, short* __restrict__ out, int n4) {
  const int stride = gridDim.x * 256;
  for (int i = blockIdx.x * 256 + threadIdx.x; i < n4; i += stride) {
    float4 v = ((const float4*)in)[i];
    s16x4 h; h[0] = f2bf(v.x); h[1] = f2bf(v.y); h[2] = f2bf(v.z); h[3] = f2bf(v.w);
    ((s16x4*)out)[i] = h;
  }
}

// ---------------------------------------------------------------------------
// Tiled bf16 GEMM, C = A(M,K) @ Bw(N,K)^T, 128x128 tile, BK=32, 4 waves.
// Epilogues: 0=BN+ReLU->bf16, 1=bias->f32+bf16, 2=bias->bf16,
//            3=bias+ReLU->bf16, 4=bias+residual->f32
// ---------------------------------------------------------------------------
enum { EPI_H1 = 0, EPI_EMB = 1, EPI_QKV = 2, EPI_FF1 = 3, EPI_RES = 4 };

template<int EPI>
__global__ __launch_bounds__(256)
void gemm_bt(const short* __restrict__ A, const short* __restrict__ Bw,
             const float* __restrict__ bias,
             const float* __restrict__ q0, const float* __restrict__ q1,
             const float* __restrict__ q2, const float* __restrict__ q3,
             const float* __restrict__ res,
             float* __restrict__ out32, short* __restrict__ out16,
             int M, int N, int K) {
  __shared__ short As[128 * 32];
  __shared__ short Bs[128 * 32];
  const int tid  = threadIdx.x;
  const int lane = tid & 63;
  const int wave = tid >> 6;
  const int m0 = blockIdx.y * 128;
  const int n0 = blockIdx.x * 128;
  const int wm = (wave >> 1) * 64;
  const int wn = (wave & 1) * 64;
  const int lrow = lane & 15;
  const int lk8  = (lane >> 4) * 8;

  f32x4 acc[4][4] = {};

  // staging addresses: wave stages 16 rows (64B each) per call, 2 calls per matrix
  const int srow = wave * 16 + (lane >> 2);
  const int scol = (lane & 3) * 8;
  const short* gA = A  + (size_t)(m0 + srow) * K + scol;
  const short* gB = Bw + (size_t)(n0 + srow) * K + scol;
  short* lA = &As[(wave * 16) * 32];
  short* lB = &Bs[(wave * 16) * 32];
  const size_t half = (size_t)64 * K;

  for (int k0 = 0; k0 < K; k0 += 32) {
    stage16(gA + k0,        lA);
    stage16(gA + half + k0, lA + 64 * 32);
    stage16(gB + k0,        lB);
    stage16(gB + half + k0, lB + 64 * 32);
    __syncthreads();
    s16x8 af[4], bfr[4];
#pragma unroll
    for (int m = 0; m < 4; ++m)
      af[m] = *(const s16x8*)&As[(wm + m * 16 + lrow) * 32 + lk8];
#pragma unroll
    for (int n = 0; n < 4; ++n)
      bfr[n] = *(const s16x8*)&Bs[(wn + n * 16 + lrow) * 32 + lk8];
#pragma unroll
    for (int m = 0; m < 4; ++m)
#pragma unroll
      for (int n = 0; n < 4; ++n)
        acc[m][n] = __builtin_amdgcn_mfma_f32_16x16x32_bf16(af[m], bfr[n], acc[m][n], 0, 0, 0);
    __syncthreads();
  }

  // epilogue: C/D layout row=(lane>>4)*4+r, col=lane&15 (per 16x16 frag)
  const int erow = m0 + wm + ((lane >> 4) << 2);
  const int ecol = n0 + wn + lrow;
  float bz[4], sc[4], sh[4];
#pragma unroll
  for (int n = 0; n < 4; ++n) {
    const int c = ecol + n * 16;
    bz[n] = bias[c];
    if constexpr (EPI == EPI_H1) {
      const float s = q0[c] * rsqrtf(q3[c] + BN_EPSF);   // bn_g * rsqrt(bn_v+eps)
      sc[n] = s;
      sh[n] = (bz[n] - q2[c]) * s + q1[c];               // (fc1_b - bn_m)*s + bn_b
    }
  }
  (void)q0; (void)q1; (void)q2; (void)q3;
#pragma unroll
  for (int m = 0; m < 4; ++m) {
#pragma unroll
    for (int n = 0; n < 4; ++n) {
#pragma unroll
      for (int r = 0; r < 4; ++r) {
        const size_t idx = (size_t)(erow + m * 16 + r) * N + (ecol + n * 16);
        float v = acc[m][n][r];
        if constexpr (EPI == EPI_H1) {
          out16[idx] = f2bf(fmaxf(v * sc[n] + sh[n], 0.f));
        } else if constexpr (EPI == EPI_EMB) {
          v += bz[n];
          out32[idx] = v;
          out16[idx] = f2bf(v);
        } else if constexpr (EPI == EPI_QKV) {
          out16[idx] = f2bf(v + bz[n]);
        } else if constexpr (EPI == EPI_FF1) {
          out16[idx] = f2bf(fmaxf(v + bz[n], 0.f));
        } else {
          out32[idx] = v + bz[n] + res[idx];
        }
      }
    }
  }
}

// ---------------------------------------------------------------------------
// Fused attention: one block per (b,h). qkv is (B*L, 3072) bf16.
// S = QK^T/sqrt(128) masked softmax, ctx = P@V  -> bf16 (B*L, 1024)
// ---------------------------------------------------------------------------
__global__ __launch_bounds__(256)
void attn_kernel(const short* __restrict__ qkv, const int* __restrict__ lens,
                 short* __restrict__ ctx) {
  __shared__ short Qs[64 * 128];   // later reused as P (stride 128, cols 0..63)
  __shared__ short Ks[64 * 128];
  __shared__ short Vt[128 * 64];   // V transposed: Vt[dh][l]
  const int tid  = threadIdx.x;
  const int lane = tid & 63;
  const int wave = tid >> 6;
  const int b = blockIdx.x >> 3;
  const int h = blockIdx.x & 7;
  const int len = lens[b];
  const size_t qb = (size_t)(b * 64) * 3072 + h * 128;

  { // stage Q,K linear via global_load_lds: 4 rounds x 4 rows/wave
    const int rr = wave * 4 + (lane >> 4);
    const int cc = (lane & 15) * 8;
#pragma unroll
    for (int r = 0; r < 4; ++r) {
      stage16(qkv + qb +        (size_t)(r * 16 + rr) * 3072 + cc, &Qs[(r * 16 + wave * 4) * 128]);
      stage16(qkv + qb + 1024 + (size_t)(r * 16 + rr) * 3072 + cc, &Ks[(r * 16 + wave * 4) * 128]);
    }
  }
  // stage V transposed (reg path, packed b32 writes covering 2 l values)
#pragma unroll
  for (int i = 0; i < 2; ++i) {
    const int c  = i * 256 + tid;    // 512 chunks of (2 rows x 8 dh)
    const int lp = c >> 4;
    const int dg = c & 15;
    const short* src = qkv + qb + 2048 + (size_t)(2 * lp) * 3072 + dg * 8;
    s16x8 v0 = *(const s16x8*)src;
    s16x8 v1 = *(const s16x8*)(src + 3072);
#pragma unroll
    for (int j = 0; j < 8; ++j) {
      uint32_t pk = ((uint32_t)(uint16_t)v0[j]) | (((uint32_t)(uint16_t)v1[j]) << 16);
      *(uint32_t*)&Vt[(dg * 8 + j) * 64 + 2 * lp] = pk;
    }
  }
  __syncthreads();

  const int lrow = lane & 15;
  const int lk8  = (lane >> 4) * 8;

  // S strip (16 rows per wave): 4 col-frags x 4 k-steps
  f32x4 sacc[4] = {};
#pragma unroll
  for (int ks = 0; ks < 4; ++ks) {
    s16x8 aq = *(const s16x8*)&Qs[(wave * 16 + lrow) * 128 + ks * 32 + lk8];
#pragma unroll
    for (int n = 0; n < 4; ++n) {
      s16x8 bk = *(const s16x8*)&Ks[(n * 16 + lrow) * 128 + ks * 32 + lk8];
      sacc[n] = __builtin_amdgcn_mfma_f32_16x16x32_bf16(aq, bk, sacc[n], 0, 0, 0);
    }
  }

  // masked softmax per row; row spread over 16 lanes (lo bits) x 4 col-frags
  const float scale = 0.08838834764831845f;  // 1/sqrt(128)
#pragma unroll
  for (int r = 0; r < 4; ++r) {
    float sv[4];
    float mx = -1e30f;
#pragma unroll
    for (int n = 0; n < 4; ++n) {
      float v = sacc[n][r] * scale;
      if (n * 16 + lrow >= len) v = -1e30f;
      sv[n] = v;
      mx = fmaxf(mx, v);
    }
    mx = fmaxf(mx, __shfl_xor(mx, 1));
    mx = fmaxf(mx, __shfl_xor(mx, 2));
    mx = fmaxf(mx, __shfl_xor(mx, 4));
    mx = fmaxf(mx, __shfl_xor(mx, 8));
    float pv[4], sum = 0.f;
#pragma unroll
    for (int n = 0; n < 4; ++n) { pv[n] = __expf(sv[n] - mx); sum += pv[n]; }
    sum += __shfl_xor(sum, 1);
    sum += __shfl_xor(sum, 2);
    sum += __shfl_xor(sum, 4);
    sum += __shfl_xor(sum, 8);
    const float inv = 1.f / sum;
    const int prow = wave * 16 + ((lane >> 4) << 2) + r;
#pragma unroll
    for (int n = 0; n < 4; ++n)
      Qs[prow * 128 + n * 16 + lrow] = f2bf(pv[n] * inv);   // P into own Q strip
  }
  __syncthreads();

  // O strip = P(16x64) @ V(64x128): 8 col-frags x 2 k-steps
  f32x4 oacc[8] = {};
#pragma unroll
  for (int ks = 0; ks < 2; ++ks) {
    s16x8 ap = *(const s16x8*)&Qs[(wave * 16 + lrow) * 128 + ks * 32 + lk8];
#pragma unroll
    for (int n = 0; n < 8; ++n) {
      s16x8 bv = *(const s16x8*)&Vt[(n * 16 + lrow) * 64 + ks * 32 + lk8];
      oacc[n] = __builtin_amdgcn_mfma_f32_16x16x32_bf16(ap, bv, oacc[n], 0, 0, 0);
    }
  }
  const size_t ob = (size_t)(b * 64) * 1024 + h * 128;
#pragma unroll
  for (int n = 0; n < 8; ++n)
#pragma unroll
    for (int r = 0; r < 4; ++r) {
      const int row = wave * 16 + ((lane >> 4) << 2) + r;
      ctx[ob + (size_t)row * 1024 + n * 16 + lrow] = f2bf(oacc[n][r]);
    }
}

// ---------------------------------------------------------------------------
// LayerNorm over 1024, one block per row; writes f32 and optionally bf16
// ---------------------------------------------------------------------------
__global__ __launch_bounds__(256)
void ln_kernel(const float* __restrict__ x, const float* __restrict__ gg,
               const float* __restrict__ bb, float* __restrict__ y32,
               short* __restrict__ y16) {
  __shared__ float red[8];
  const int tid = threadIdx.x;
  const int lane = tid & 63;
  const int wave = tid >> 6;
  const size_t base = (size_t)blockIdx.x * 1024;
  float4 v = ((const float4*)(x + base))[tid];
  float s1 = v.x + v.y + v.z + v.w;
  float s2 = v.x * v.x + v.y * v.y + v.z * v.z + v.w * v.w;
#pragma unroll
  for (int o = 1; o < 64; o <<= 1) { s1 += __shfl_xor(s1, o); s2 += __shfl_xor(s2, o); }
  if (lane == 0) { red[wave] = s1; red[wave + 4] = s2; }
  __syncthreads();
  s1 = red[0] + red[1] + red[2] + red[3];
  s2 = red[4] + red[5] + red[6] + red[7];
  const float mu  = s1 * (1.f / 1024.f);
  const float var = fmaxf(s2 * (1.f / 1024.f) - mu * mu, 0.f);
  const float rs  = rsqrtf(var + LN_EPSF);
  float4 g4 = ((const float4*)gg)[tid];
  float4 b4 = ((const float4*)bb)[tid];
  const float o0 = (v.x - mu) * rs * g4.x + b4.x;
  const float o1 = (v.y - mu) * rs * g4.y + b4.y;
  const float o2 = (v.z - mu) * rs * g4.z + b4.z;
  const float o3 = (v.w - mu) * rs * g4.w + b4.w;
  ((float4*)(y32 + base))[tid] = make_float4(o0, o1, o2, o3);
  if (y16) {
    s16x4 hh; hh[0] = f2bf(o0); hh[1] = f2bf(o1); hh[2] = f2bf(o2); hh[3] = f2bf(o3);
    ((s16x4*)(y16 + base))[tid] = hh;
  }
}

// ---------------------------------------------------------------------------
// top-2 mean over valid tokens, per (b, d)
// ---------------------------------------------------------------------------
__global__ __launch_bounds__(256)
void topk_kernel(const float* __restrict__ emb, const int* __restrict__ lens,
                 float* __restrict__ er) {
  const int b = blockIdx.x;
  const int len = lens[b];
  const int tid = threadIdx.x;
#pragma unroll
  for (int j = 0; j < 4; ++j) {
    const int d = j * 256 + tid;
    const float* p = emb + (size_t)b * 64 * 1024 + d;
    float m1 = -3.0e38f, m2 = -3.0e38f;
    for (int l = 0; l < len; ++l) {
      const float v = p[(size_t)l * 1024];
      if (v > m1) { m2 = m1; m1 = v; }
      else        { m2 = fmaxf(m2, v); }
    }
    er[(size_t)b * 1024 + d] = 0.5f * (m1 + m2);
  }
}

// ---------------------------------------------------------------------------
// avg-pool over valid tokens + 0.5/0.5 mix with emb_res + L2 normalize
// ---------------------------------------------------------------------------
__global__ __launch_bounds__(256)
void final_kernel(const float* __restrict__ x2, const float* __restrict__ er,
                  const int* __restrict__ lens, float* __restrict__ out) {
  __shared__ float red[4];
  const int tid = threadIdx.x;
  const int lane = tid & 63;
  const int wave = tid >> 6;
  const int b = blockIdx.x;
  const int len = lens[b];
  const float* p = x2 + (size_t)b * 64 * 1024;
  float a0 = 0, a1 = 0, a2 = 0, a3 = 0;
  for (int l = 0; l < len; ++l) {
    float4 v = ((const float4*)(p + (size_t)l * 1024))[tid];
    a0 += v.x; a1 += v.y; a2 += v.z; a3 += v.w;
  }
  const float inv = 0.5f / (float)len;
  float4 e4 = ((const float4*)(er + (size_t)b * 1024))[tid];
  const float o0 = 0.5f * e4.x + a0 * inv;
  const float o1 = 0.5f * e4.y + a1 * inv;
  const float o2 = 0.5f * e4.z + a2 * inv;
  const float o3 = 0.5f * e4.w + a3 * inv;
  float ss = o0 * o0 + o1 * o1 + o2 * o2 + o3 * o3;
#pragma unroll
  for (int o = 1; o < 64; o <<= 1) ss += __shfl_xor(ss, o);
  if (lane == 0) red[wave] = ss;
  __syncthreads();
  ss = red[0] + red[1] + red[2] + red[3];
  const float nrm = 1.f / (sqrtf(ss) + 1e-8f);
  ((float4*)(out + (size_t)b * 1024))[tid] = make_float4(o0 * nrm, o1 * nrm, o2 * nrm, o3 * nrm);
}

// ---------------------------------------------------------------------------
extern "C" void kernel_launch(void* const* d_in, const int* in_sizes, int n_in,
                              void* d_out, int out_size, void* d_ws, size_t ws_size,
                              hipStream_t stream) {
  (void)in_sizes; (void)n_in; (void)out_size; (void)ws_size;
  const float* images = (const float*)d_in[0];
  const int*   lens   = (const int*)d_in[1];
  const float* fc1_w = (const float*)d_in[2];
  const float* fc1_b = (const float*)d_in[3];
  const float* bn_g  = (const float*)d_in[4];
  const float* bn_b  = (const float*)d_in[5];
  const float* bn_m  = (const float*)d_in[6];
  const float* bn_v  = (const float*)d_in[7];
  const float* fc2_w = (const float*)d_in[8];
  const float* fc2_b = (const float*)d_in[9];
  const float* in_w  = (const float*)d_in[10];
  const float* in_b  = (const float*)d_in[11];
  const float* out_w = (const float*)d_in[12];
  const float* out_b = (const float*)d_in[13];
  const float* ln1_g = (const float*)d_in[14];
  const float* ln1_b = (const float*)d_in[15];
  const float* ff1_w = (const float*)d_in[16];
  const float* ff1_b = (const float*)d_in[17];
  const float* ff2_w = (const float*)d_in[18];
  const float* ff2_b = (const float*)d_in[19];
  const float* ln2_g = (const float*)d_in[20];
  const float* ln2_b = (const float*)d_in[21];
  float* out = (float*)d_out;

  char* ws = (char*)d_ws;
  // workspace layout (peak 335,544,320 B = 320 MiB, with reuse)
  const size_t OFF_IMG16 = 0;                          // 67108864
  const size_t OFF_FC1W  = 67108864;                   // 2097152
  const size_t OFF_FC2W  = OFF_FC1W + 2097152;         // 1048576
  const size_t OFF_INW   = OFF_FC2W + 1048576;         // 6291456
  const size_t OFF_OUTW  = OFF_INW  + 6291456;         // 2097152
  const size_t OFF_FF1W  = OFF_OUTW + 2097152;         // 2097152
  const size_t OFF_FF2W  = OFF_FF1W + 2097152;         // 2097152
  const size_t OFF_H1    = OFF_FF2W + 2097152;         // 16777216
  const size_t OFF_EMB32 = OFF_H1 + 16777216;          // 67108864
  const size_t OFF_EMB16 = OFF_EMB32 + 67108864;       // 33554432
  const size_t OFF_QKV   = OFF_EMB16 + 33554432;       // 100663296
  const size_t OFF_CTX   = OFF_QKV + 100663296;        // 33554432
  const size_t OFF_ERES  = OFF_CTX + 33554432;         // 1048576

  short* img16  = (short*)(ws + OFF_IMG16);
  short* fc1w16 = (short*)(ws + OFF_FC1W);
  short* fc2w16 = (short*)(ws + OFF_FC2W);
  short* inw16  = (short*)(ws + OFF_INW);
  short* outw16 = (short*)(ws + OFF_OUTW);
  short* ff1w16 = (short*)(ws + OFF_FF1W);
  short* ff2w16 = (short*)(ws + OFF_FF2W);
  short* h1     = (short*)(ws + OFF_H1);
  float* emb32  = (float*)(ws + OFF_EMB32);
  short* emb16  = (short*)(ws + OFF_EMB16);
  short* qkv16  = (short*)(ws + OFF_QKV);
  short* ctx16  = (short*)(ws + OFF_CTX);
  float* embres = (float*)(ws + OFF_ERES);
  // reuses (lifetimes disjoint):
  float* x1s = (float*)(ws + OFF_IMG16);   // pre-LN1 sum   (img16 dead)
  float* x1  = emb32;                      // post-LN1 f32  (emb32 dead)
  short* x1h = emb16;                      // post-LN1 bf16 (emb16 dead)
  short* ffh = ctx16;                      // ffn hidden    (ctx16 dead)
  float* x2s = (float*)(ws + OFF_IMG16);   // pre-LN2 sum   (x1s dead)
  float* x2  = (float*)(ws + OFF_QKV);     // post-LN2 f32  (qkv16 dead)

  const dim3 blk(256);

  // converts
  cvt_kernel<<<2048, blk, 0, stream>>>(images, img16, 33554432 / 4);
  cvt_kernel<<<512,  blk, 0, stream>>>(fc1_w, fc1w16, 1048576 / 4);
  cvt_kernel<<<512,  blk, 0, stream>>>(fc2_w, fc2w16, 524288 / 4);
  cvt_kernel<<<1024, blk, 0, stream>>>(in_w,  inw16,  3145728 / 4);
  cvt_kernel<<<512,  blk, 0, stream>>>(out_w, outw16, 1048576 / 4);
  cvt_kernel<<<512,  blk, 0, stream>>>(ff1_w, ff1w16, 1048576 / 4);
  cvt_kernel<<<512,  blk, 0, stream>>>(ff2_w, ff2w16, 1048576 / 4);

  // fc1 + BN + ReLU -> h1 (bf16)
  gemm_bt<EPI_H1><<<dim3(4, 128), blk, 0, stream>>>(
      img16, fc1w16, fc1_b, bn_g, bn_b, bn_m, bn_v, nullptr, nullptr, h1,
      16384, 512, 2048);
  // fc2 -> emb (f32 + bf16)
  gemm_bt<EPI_EMB><<<dim3(8, 128), blk, 0, stream>>>(
      h1, fc2w16, fc2_b, nullptr, nullptr, nullptr, nullptr, nullptr,
      emb32, emb16, 16384, 1024, 512);
  // top-2 pooling
  topk_kernel<<<256, blk, 0, stream>>>(emb32, lens, embres);
  // qkv projection
  gemm_bt<EPI_QKV><<<dim3(24, 128), blk, 0, stream>>>(
      emb16, inw16, in_b, nullptr, nullptr, nullptr, nullptr, nullptr,
      nullptr, qkv16, 16384, 3072, 1024);
  // attention
  attn_kernel<<<2048, blk, 0, stream>>>(qkv16, lens, ctx16);
  // out projection + residual(emb) -> pre-LN1
  gemm_bt<EPI_RES><<<dim3(8, 128), blk, 0, stream>>>(
      ctx16, outw16, out_b, nullptr, nullptr, nullptr, nullptr, emb32,
      x1s, nullptr, 16384, 1024, 1024);
  ln_kernel<<<16384, blk, 0, stream>>>(x1s, ln1_g, ln1_b, x1, x1h);
  // ffn
  gemm_bt<EPI_FF1><<<dim3(8, 128), blk, 0, stream>>>(
      x1h, ff1w16, ff1_b, nullptr, nullptr, nullptr, nullptr, nullptr,
      nullptr, ffh, 16384, 1024, 1024);
  gemm_bt<EPI_RES><<<dim3(8, 128), blk, 0, stream>>>(
      ffh, ff2w16, ff2_b, nullptr, nullptr, nullptr, nullptr, x1,
      x2s, nullptr, 16384, 1024, 1024);
  ln_kernel<<<16384, blk, 0, stream>>>(x2s, ln2_g, ln2_b, x2, nullptr);
  // pooling + mix + normalize
  final_kernel<<<256, blk, 0, stream>>>(x2, embres, lens, out);
}

// Round 2
// 468.589 us; speedup vs baseline: 1.4745x; 1.4745x over previous
//
#include <hip/hip_runtime.h>
#include <stdint.h>
#include <stddef.h>

// ---------------------------------------------------------------------------
// EncoderImageAggr: bf16-MFMA pipeline for MI355X (gfx950)
// B=256 L=64 IMG_DIM=2048 D=1024 H=8 DH=128. All GEMMs are C = A @ W^T.
// Round 2: 256x256 BK=64 4-phase pipelined GEMM (T1+T2+T3+T4+T5),
//          topk fused into fc2 epilogue, LN2+pool+normalize fused.
// ---------------------------------------------------------------------------

typedef short s16x8 __attribute__((ext_vector_type(8)));
typedef short s16x4 __attribute__((ext_vector_type(4)));
typedef float f32x4 __attribute__((ext_vector_type(4)));

#define LN_EPSF 1e-5f
#define BN_EPSF 1e-5f

__device__ __forceinline__ short f2bf(float f) {
  union { float f; uint32_t u; } x; x.f = f;
  uint32_t r = x.u + 0x7fffu + ((x.u >> 16) & 1u);   // RNE
  return (short)(r >> 16);
}

typedef const __attribute__((address_space(1))) short glb_s16_t;
typedef __attribute__((address_space(3))) short lds_s16_t;

__device__ __forceinline__ void stage16(const short* g, short* l) {
  __builtin_amdgcn_global_load_lds((glb_s16_t*)g, (lds_s16_t*)l, 16, 0, 0);
}

// involution swizzle for [256][32]-bf16 (64B-row) LDS half-tiles:
// flips byte bits 4-5 with (untouched) bits 7-8 -> <=2-way bank conflicts
__device__ __forceinline__ int swz(int off) {
  return off ^ (((off >> 7) & 3) << 4);
}

enum { EPI_H1 = 0, EPI_EMB = 1, EPI_QKV = 2, EPI_FF1 = 3, EPI_RES = 4 };

// ---------------------------------------------------------------------------
// fp32 -> bf16 converts
// ---------------------------------------------------------------------------
__global__ __launch_bounds__(256)
void cvt_kernel(const float* __restrict__ in, short* __restrict__ out, int n4) {
  const int stride = gridDim.x * 256;
  for (int i = blockIdx.x * 256 + threadIdx.x; i < n4; i += stride) {
    float4 v = ((const float4*)in)[i];
    s16x4 h; h[0] = f2bf(v.x); h[1] = f2bf(v.y); h[2] = f2bf(v.z); h[3] = f2bf(v.w);
    ((s16x4*)out)[i] = h;
  }
}

struct CvtArgs { const float* src[6]; short* dst[6]; int n4[6]; };

__global__ __launch_bounds__(256)
void cvt6_kernel(CvtArgs a) {
#pragma unroll
  for (int s = 0; s < 6; ++s) {
    const int n = a.n4[s];
    const float4* in = (const float4*)a.src[s];
    s16x4* outp = (s16x4*)a.dst[s];
    for (int i = blockIdx.x * 256 + threadIdx.x; i < n; i += gridDim.x * 256) {
      float4 v = in[i];
      s16x4 h; h[0] = f2bf(v.x); h[1] = f2bf(v.y); h[2] = f2bf(v.z); h[3] = f2bf(v.w);
      outp[i] = h;
    }
  }
}

// ---------------------------------------------------------------------------
// 256x256 BK=64 pipelined GEMM, C = A(M,K) @ Bw(N,K)^T. 512 thr = 8 waves
// (2Mx4N), per-wave 128x64 output. LDS ring: per matrix 4 half-slots of
// [256][32] bf16 (16KB each) = 2 K-tile buffers x 2 K-halves. One half-tile
// staged per phase; counted vmcnt(8) at K-half boundaries keeps 4 half-tiles
// (8 global_load_lds per thread) in flight across barriers.
// ---------------------------------------------------------------------------
template<int EPI>
__global__ __launch_bounds__(512, 2)
void gemm256(const short* __restrict__ A, const short* __restrict__ Bw,
             const float* __restrict__ bias, const float* __restrict__ res,
             const int* __restrict__ lens, float* __restrict__ embres,
             float* __restrict__ out32, short* __restrict__ out16,
             int M, int N, int K) {
  extern __shared__ char smem[];                 // 131072 B: A slots, then B
  (void)M;
  const int tid  = threadIdx.x;
  const int lane = tid & 63;
  const int w    = tid >> 6;
  const int wr   = w >> 2;                       // 0..1
  const int wc   = w & 3;                        // 0..3
  const int lrow = lane & 15;
  const int cg   = lane >> 4;                    // 0..3
  const int NT   = K >> 6;
  const int gx   = gridDim.x;

  // T1: bijective XCD swizzle (nwg % 8 == 0 for all our launches)
  int wg = blockIdx.y * gx + blockIdx.x;
  {
    const int cpx = (gx * gridDim.y) >> 3;
    wg = (wg & 7) * cpx + (wg >> 3);
  }
  const int m0 = (wg / gx) * 256;
  const int n0 = (wg % gx) * 256;

  // per-thread staging source offsets (bytes within matrix), j = 0,1
  const int ldb = K * 2;
  size_t gA[2], gB[2];
#pragma unroll
  for (int j = 0; j < 2; ++j) {
    const int p = tid * 16 + j * 8192;
    const int l = swz(p);
    const int row = l >> 6, colb = l & 63;
    gA[j] = (size_t)(m0 + row) * ldb + colb;
    gB[j] = (size_t)(n0 + row) * ldb + colb;
  }
  const char* Ab = (const char*)A;
  const char* Bb = (const char*)Bw;
  char* ldsA = smem;
  char* ldsB = smem + 65536;
  const int wofs = w * 1024;

  auto stageA = [&](int T, int KH) {
    const int rg = (((T & 1) * 2 + KH) << 14) + wofs;
    const int ko = T * 128 + KH * 64;
    stage16((const short*)(Ab + gA[0] + ko), (short*)(ldsA + rg));
    stage16((const short*)(Ab + gA[1] + ko), (short*)(ldsA + rg + 8192));
  };
  auto stageB = [&](int T, int KH) {
    const int rg = (((T & 1) * 2 + KH) << 14) + wofs;
    const int ko = T * 128 + KH * 64;
    stage16((const short*)(Bb + gB[0] + ko), (short*)(ldsB + rg));
    stage16((const short*)(Bb + gB[1] + ko), (short*)(ldsB + rg + 8192));
  };

  // per-thread swizzled ds_read offsets
  int offA[8], offB[4];
#pragma unroll
  for (int mf = 0; mf < 8; ++mf)
    offA[mf] = swz((wr * 128 + mf * 16 + lrow) * 64 + cg * 16);
#pragma unroll
  for (int nf = 0; nf < 4; ++nf)
    offB[nf] = swz((wc * 64 + nf * 16 + lrow) * 64 + cg * 16);

  f32x4 acc[8][4] = {};

  // prologue: tiles 0 and 1 fully staged (16 loads/thread)
#pragma unroll
  for (int tt = 0; tt < 2; ++tt) {
    stageA(tt, 0); stageB(tt, 0); stageA(tt, 1); stageB(tt, 1);
  }

  s16x8 bf[4];
  for (int t = 0; t < NT; ++t) {
    const int bb = t & 1;
    const char* rA0 = ldsA + ((bb * 2 + 0) << 14);
    const char* rA1 = ldsA + ((bb * 2 + 1) << 14);
    const char* rB0 = ldsB + ((bb * 2 + 0) << 14);
    const char* rB1 = ldsB + ((bb * 2 + 1) << 14);
    s16x8 af[4];

    // ---- phase q0: ks=0, mf 0..3 ----
    if (t + 1 < NT) { asm volatile("s_waitcnt vmcnt(8)" ::: "memory"); }
    else            { asm volatile("s_waitcnt vmcnt(4)" ::: "memory"); }
    __builtin_amdgcn_s_barrier();
    __builtin_amdgcn_sched_barrier(0);
#pragma unroll
    for (int nf = 0; nf < 4; ++nf) bf[nf] = *(const s16x8*)(rB0 + offB[nf]);
#pragma unroll
    for (int mf = 0; mf < 4; ++mf) af[mf] = *(const s16x8*)(rA0 + offA[mf]);
    if (t >= 1 && t + 1 < NT) stageA(t + 1, 1);
    __builtin_amdgcn_s_setprio(1);
#pragma unroll
    for (int mf = 0; mf < 4; ++mf)
#pragma unroll
      for (int nf = 0; nf < 4; ++nf)
        acc[mf][nf] = __builtin_amdgcn_mfma_f32_16x16x32_bf16(af[mf], bf[nf], acc[mf][nf], 0, 0, 0);
    __builtin_amdgcn_s_setprio(0);

    // ---- phase q1: ks=0, mf 4..7 ----
    __builtin_amdgcn_s_barrier();
    __builtin_amdgcn_sched_barrier(0);
#pragma unroll
    for (int mf = 0; mf < 4; ++mf) af[mf] = *(const s16x8*)(rA0 + offA[mf + 4]);
    if (t >= 1 && t + 1 < NT) stageB(t + 1, 1);
    __builtin_amdgcn_s_setprio(1);
#pragma unroll
    for (int mf = 0; mf < 4; ++mf)
#pragma unroll
      for (int nf = 0; nf < 4; ++nf)
        acc[mf + 4][nf] = __builtin_amdgcn_mfma_f32_16x16x32_bf16(af[mf], bf[nf], acc[mf + 4][nf], 0, 0, 0);
    __builtin_amdgcn_s_setprio(0);

    // ---- phase q2: ks=1, mf 0..3 ----
    if (t + 1 < NT) { asm volatile("s_waitcnt vmcnt(8)" ::: "memory"); }
    else            { asm volatile("s_waitcnt vmcnt(0)" ::: "memory"); }
    __builtin_amdgcn_s_barrier();
    __builtin_amdgcn_sched_barrier(0);
#pragma unroll
    for (int nf = 0; nf < 4; ++nf) bf[nf] = *(const s16x8*)(rB1 + offB[nf]);
#pragma unroll
    for (int mf = 0; mf < 4; ++mf) af[mf] = *(const s16x8*)(rA1 + offA[mf]);
    if (t + 2 < NT) stageA(t + 2, 0);
    __builtin_amdgcn_s_setprio(1);
#pragma unroll
    for (int mf = 0; mf < 4; ++mf)
#pragma unroll
      for (int nf = 0; nf < 4; ++nf)
        acc[mf][nf] = __builtin_amdgcn_mfma_f32_16x16x32_bf16(af[mf], bf[nf], acc[mf][nf], 0, 0, 0);
    __builtin_amdgcn_s_setprio(0);

    // ---- phase q3: ks=1, mf 4..7 ----
    __builtin_amdgcn_s_barrier();
    __builtin_amdgcn_sched_barrier(0);
#pragma unroll
    for (int mf = 0; mf < 4; ++mf) af[mf] = *(const s16x8*)(rA1 + offA[mf + 4]);
    if (t + 2 < NT) stageB(t + 2, 0);
    __builtin_amdgcn_s_setprio(1);
#pragma unroll
    for (int mf = 0; mf < 4; ++mf)
#pragma unroll
      for (int nf = 0; nf < 4; ++nf)
        acc[mf + 4][nf] = __builtin_amdgcn_mfma_f32_16x16x32_bf16(af[mf], bf[nf], acc[mf + 4][nf], 0, 0, 0);
    __builtin_amdgcn_s_setprio(0);
  }

  // ---- epilogue (C/D layout: row=(lane>>4)*4+r, col=lane&15 per 16x16) ----
  const int ecol0 = n0 + wc * 64 + lrow;
  float bz[4];
#pragma unroll
  for (int nf = 0; nf < 4; ++nf) bz[nf] = bias[ecol0 + nf * 16];
  const int erow0 = m0 + wr * 128 + (cg << 2);

  float t1[2][4], t2[2][4];
  int len0 = 0, len1 = 0;
  if constexpr (EPI == EPI_EMB) {
    const int bat0 = (m0 >> 6) + wr * 2;
    len0 = lens[bat0]; len1 = lens[bat0 + 1];
#pragma unroll
    for (int g = 0; g < 2; ++g)
#pragma unroll
      for (int nf = 0; nf < 4; ++nf) { t1[g][nf] = -3.0e38f; t2[g][nf] = -3.0e38f; }
  }

#pragma unroll
  for (int mf = 0; mf < 8; ++mf) {
#pragma unroll
    for (int nf = 0; nf < 4; ++nf) {
#pragma unroll
      for (int r = 0; r < 4; ++r) {
        const int row = erow0 + mf * 16 + r;
        const size_t idx = (size_t)row * N + (ecol0 + nf * 16);
        const float v = acc[mf][nf][r] + bz[nf];
        if constexpr (EPI == EPI_EMB) {
          out32[idx] = v;
          out16[idx] = f2bf(v);
          const int g = mf >> 2;
          const int token = (mf & 3) * 16 + (cg << 2) + r;
          const float vm = (token < (g ? len1 : len0)) ? v : -3.0e38f;
          float* a1 = &t1[g][nf];
          float* a2 = &t2[g][nf];
          if (vm > *a1) { *a2 = *a1; *a1 = vm; }
          else if (vm > *a2) { *a2 = vm; }
        } else if constexpr (EPI == EPI_QKV) {
          out16[idx] = f2bf(v);
        } else if constexpr (EPI == EPI_FF1) {
          out16[idx] = f2bf(fmaxf(v, 0.f));
        } else {  // EPI_RES
          out32[idx] = v + res[idx];
        }
      }
    }
  }

  if constexpr (EPI == EPI_EMB) {
    const int bat0 = (m0 >> 6) + wr * 2;
#pragma unroll
    for (int g = 0; g < 2; ++g)
#pragma unroll
      for (int nf = 0; nf < 4; ++nf) {
        float a1 = t1[g][nf], a2 = t2[g][nf];
#pragma unroll
        for (int d = 16; d <= 32; d <<= 1) {
          const float b1 = __shfl_xor(a1, d);
          const float b2 = __shfl_xor(a2, d);
          const float n1 = fmaxf(a1, b1);
          const float n2 = fmaxf(fminf(a1, b1), fmaxf(a2, b2));
          a1 = n1; a2 = n2;
        }
        if (cg == 0)
          embres[(size_t)(bat0 + g) * 1024 + ecol0 + nf * 16] = 0.5f * (a1 + a2);
      }
  }
}

// ---------------------------------------------------------------------------
// old 128x128 GEMM kept for fc1 (N=512 -> 512 blocks; 256-tile would give 128)
// ---------------------------------------------------------------------------
__global__ __launch_bounds__(256)
void gemm_bt_h1(const short* __restrict__ A, const short* __restrict__ Bw,
                const float* __restrict__ bias,
                const float* __restrict__ bn_g, const float* __restrict__ bn_b,
                const float* __restrict__ bn_m, const float* __restrict__ bn_v,
                short* __restrict__ out16, int M, int N, int K) {
  __shared__ short As[128 * 32];
  __shared__ short Bs[128 * 32];
  (void)M;
  const int tid  = threadIdx.x;
  const int lane = tid & 63;
  const int wave = tid >> 6;
  const int m0 = blockIdx.y * 128;
  const int n0 = blockIdx.x * 128;
  const int wm = (wave >> 1) * 64;
  const int wn = (wave & 1) * 64;
  const int lrow = lane & 15;
  const int lk8  = (lane >> 4) * 8;

  f32x4 acc[4][4] = {};

  const int srow = wave * 16 + (lane >> 2);
  const int scol = (lane & 3) * 8;
  const short* gA = A  + (size_t)(m0 + srow) * K + scol;
  const short* gB = Bw + (size_t)(n0 + srow) * K + scol;
  short* lA = &As[(wave * 16) * 32];
  short* lB = &Bs[(wave * 16) * 32];
  const size_t half = (size_t)64 * K;

  for (int k0 = 0; k0 < K; k0 += 32) {
    stage16(gA + k0,        lA);
    stage16(gA + half + k0, lA + 64 * 32);
    stage16(gB + k0,        lB);
    stage16(gB + half + k0, lB + 64 * 32);
    __syncthreads();
    s16x8 af[4], bfr[4];
#pragma unroll
    for (int m = 0; m < 4; ++m)
      af[m] = *(const s16x8*)&As[(wm + m * 16 + lrow) * 32 + lk8];
#pragma unroll
    for (int n = 0; n < 4; ++n)
      bfr[n] = *(const s16x8*)&Bs[(wn + n * 16 + lrow) * 32 + lk8];
#pragma unroll
    for (int m = 0; m < 4; ++m)
#pragma unroll
      for (int n = 0; n < 4; ++n)
        acc[m][n] = __builtin_amdgcn_mfma_f32_16x16x32_bf16(af[m], bfr[n], acc[m][n], 0, 0, 0);
    __syncthreads();
  }

  const int erow = m0 + wm + ((lane >> 4) << 2);
  const int ecol = n0 + wn + lrow;
  float sc[4], sh[4];
#pragma unroll
  for (int n = 0; n < 4; ++n) {
    const int c = ecol + n * 16;
    const float s = bn_g[c] * rsqrtf(bn_v[c] + BN_EPSF);
    sc[n] = s;
    sh[n] = (bias[c] - bn_m[c]) * s + bn_b[c];
  }
#pragma unroll
  for (int m = 0; m < 4; ++m)
#pragma unroll
    for (int n = 0; n < 4; ++n)
#pragma unroll
      for (int r = 0; r < 4; ++r) {
        const size_t idx = (size_t)(erow + m * 16 + r) * N + (ecol + n * 16);
        out16[idx] = f2bf(fmaxf(acc[m][n][r] * sc[n] + sh[n], 0.f));
      }
}

// ---------------------------------------------------------------------------
// Fused attention: one block per (b,h). qkv is (B*L, 3072) bf16.
// ---------------------------------------------------------------------------
__global__ __launch_bounds__(256)
void attn_kernel(const short* __restrict__ qkv, const int* __restrict__ lens,
                 short* __restrict__ ctx) {
  __shared__ short Qs[64 * 128];
  __shared__ short Ks[64 * 128];
  __shared__ short Vt[128 * 64];
  const int tid  = threadIdx.x;
  const int lane = tid & 63;
  const int wave = tid >> 6;
  const int b = blockIdx.x >> 3;
  const int h = blockIdx.x & 7;
  const int len = lens[b];
  const size_t qb = (size_t)(b * 64) * 3072 + h * 128;

  {
    const int rr = wave * 4 + (lane >> 4);
    const int cc = (lane & 15) * 8;
#pragma unroll
    for (int r = 0; r < 4; ++r) {
      stage16(qkv + qb +        (size_t)(r * 16 + rr) * 3072 + cc, &Qs[(r * 16 + wave * 4) * 128]);
      stage16(qkv + qb + 1024 + (size_t)(r * 16 + rr) * 3072 + cc, &Ks[(r * 16 + wave * 4) * 128]);
    }
  }
#pragma unroll
  for (int i = 0; i < 2; ++i) {
    const int c  = i * 256 + tid;
    const int lp = c >> 4;
    const int dg = c & 15;
    const short* src = qkv + qb + 2048 + (size_t)(2 * lp) * 3072 + dg * 8;
    s16x8 v0 = *(const s16x8*)src;
    s16x8 v1 = *(const s16x8*)(src + 3072);
#pragma unroll
    for (int j = 0; j < 8; ++j) {
      uint32_t pk = ((uint32_t)(uint16_t)v0[j]) | (((uint32_t)(uint16_t)v1[j]) << 16);
      *(uint32_t*)&Vt[(dg * 8 + j) * 64 + 2 * lp] = pk;
    }
  }
  __syncthreads();

  const int lrow = lane & 15;
  const int lk8  = (lane >> 4) * 8;

  f32x4 sacc[4] = {};
#pragma unroll
  for (int ks = 0; ks < 4; ++ks) {
    s16x8 aq = *(const s16x8*)&Qs[(wave * 16 + lrow) * 128 + ks * 32 + lk8];
#pragma unroll
    for (int n = 0; n < 4; ++n) {
      s16x8 bk = *(const s16x8*)&Ks[(n * 16 + lrow) * 128 + ks * 32 + lk8];
      sacc[n] = __builtin_amdgcn_mfma_f32_16x16x32_bf16(aq, bk, sacc[n], 0, 0, 0);
    }
  }

  const float scale = 0.08838834764831845f;
#pragma unroll
  for (int r = 0; r < 4; ++r) {
    float sv[4];
    float mx = -1e30f;
#pragma unroll
    for (int n = 0; n < 4; ++n) {
      float v = sacc[n][r] * scale;
      if (n * 16 + lrow >= len) v = -1e30f;
      sv[n] = v;
      mx = fmaxf(mx, v);
    }
    mx = fmaxf(mx, __shfl_xor(mx, 1));
    mx = fmaxf(mx, __shfl_xor(mx, 2));
    mx = fmaxf(mx, __shfl_xor(mx, 4));
    mx = fmaxf(mx, __shfl_xor(mx, 8));
    float pv[4], sum = 0.f;
#pragma unroll
    for (int n = 0; n < 4; ++n) { pv[n] = __expf(sv[n] - mx); sum += pv[n]; }
    sum += __shfl_xor(sum, 1);
    sum += __shfl_xor(sum, 2);
    sum += __shfl_xor(sum, 4);
    sum += __shfl_xor(sum, 8);
    const float inv = 1.f / sum;
    const int prow = wave * 16 + ((lane >> 4) << 2) + r;
#pragma unroll
    for (int n = 0; n < 4; ++n)
      Qs[prow * 128 + n * 16 + lrow] = f2bf(pv[n] * inv);
  }
  __syncthreads();

  f32x4 oacc[8] = {};
#pragma unroll
  for (int ks = 0; ks < 2; ++ks) {
    s16x8 ap = *(const s16x8*)&Qs[(wave * 16 + lrow) * 128 + ks * 32 + lk8];
#pragma unroll
    for (int n = 0; n < 8; ++n) {
      s16x8 bv = *(const s16x8*)&Vt[(n * 16 + lrow) * 64 + ks * 32 + lk8];
      oacc[n] = __builtin_amdgcn_mfma_f32_16x16x32_bf16(ap, bv, oacc[n], 0, 0, 0);
    }
  }
  const size_t ob = (size_t)(b * 64) * 1024 + h * 128;
#pragma unroll
  for (int n = 0; n < 8; ++n)
#pragma unroll
    for (int r = 0; r < 4; ++r) {
      const int row = wave * 16 + ((lane >> 4) << 2) + r;
      ctx[ob + (size_t)row * 1024 + n * 16 + lrow] = f2bf(oacc[n][r]);
    }
}

// ---------------------------------------------------------------------------
// LayerNorm over 1024 (LN1), one block per row; writes f32 + bf16
// ---------------------------------------------------------------------------
__global__ __launch_bounds__(256)
void ln_kernel(const float* __restrict__ x, const float* __restrict__ gg,
               const float* __restrict__ bb, float* __restrict__ y32,
               short* __restrict__ y16) {
  __shared__ float red[8];
  const int tid = threadIdx.x;
  const int lane = tid & 63;
  const int wave = tid >> 6;
  const size_t base = (size_t)blockIdx.x * 1024;
  float4 v = ((const float4*)(x + base))[tid];
  float s1 = v.x + v.y + v.z + v.w;
  float s2 = v.x * v.x + v.y * v.y + v.z * v.z + v.w * v.w;
#pragma unroll
  for (int o = 1; o < 64; o <<= 1) { s1 += __shfl_xor(s1, o); s2 += __shfl_xor(s2, o); }
  if (lane == 0) { red[wave] = s1; red[wave + 4] = s2; }
  __syncthreads();
  s1 = red[0] + red[1] + red[2] + red[3];
  s2 = red[4] + red[5] + red[6] + red[7];
  const float mu  = s1 * (1.f / 1024.f);
  const float var = fmaxf(s2 * (1.f / 1024.f) - mu * mu, 0.f);
  const float rs  = rsqrtf(var + LN_EPSF);
  float4 g4 = ((const float4*)gg)[tid];
  float4 b4 = ((const float4*)bb)[tid];
  const float o0 = (v.x - mu) * rs * g4.x + b4.x;
  const float o1 = (v.y - mu) * rs * g4.y + b4.y;
  const float o2 = (v.z - mu) * rs * g4.z + b4.z;
  const float o3 = (v.w - mu) * rs * g4.w + b4.w;
  ((float4*)(y32 + base))[tid] = make_float4(o0, o1, o2, o3);
  s16x4 hh; hh[0] = f2bf(o0); hh[1] = f2bf(o1); hh[2] = f2bf(o2); hh[3] = f2bf(o3);
  ((s16x4*)(y16 + base))[tid] = hh;
}

// ---------------------------------------------------------------------------
// fused LN2 + avg-pool over valid tokens + 0.5/0.5 mix + L2 normalize.
// one block (4 waves) per batch; wave handles rows w, w+4, ...
// ---------------------------------------------------------------------------
__global__ __launch_bounds__(256)
void ln2_final_kernel(const float* __restrict__ x, const float* __restrict__ gg,
                      const float* __restrict__ bb, const float* __restrict__ er,
                      const int* __restrict__ lens, float* __restrict__ out) {
  __shared__ float part[4][1024];
  __shared__ float red[4];
  const int tid = threadIdx.x, lane = tid & 63, w = tid >> 6;
  const int b = blockIdx.x, len = lens[b];
  float4 g4[4], b4[4];
#pragma unroll
  for (int k = 0; k < 4; ++k) {
    g4[k] = ((const float4*)gg)[k * 64 + lane];
    b4[k] = ((const float4*)bb)[k * 64 + lane];
  }
  float4 acc[4];
#pragma unroll
  for (int k = 0; k < 4; ++k) acc[k] = make_float4(0.f, 0.f, 0.f, 0.f);

  for (int l = w; l < len; l += 4) {
    const float4* row = (const float4*)(x + ((size_t)b * 64 + l) * 1024);
    float4 v[4]; float s1 = 0.f, s2 = 0.f;
#pragma unroll
    for (int k = 0; k < 4; ++k) {
      v[k] = row[k * 64 + lane];
      s1 += v[k].x + v[k].y + v[k].z + v[k].w;
      s2 += v[k].x * v[k].x + v[k].y * v[k].y + v[k].z * v[k].z + v[k].w * v[k].w;
    }
#pragma unroll
    for (int o = 1; o < 64; o <<= 1) { s1 += __shfl_xor(s1, o); s2 += __shfl_xor(s2, o); }
    const float mu = s1 * (1.f / 1024.f);
    const float rs = rsqrtf(fmaxf(s2 * (1.f / 1024.f) - mu * mu, 0.f) + LN_EPSF);
#pragma unroll
    for (int k = 0; k < 4; ++k) {
      acc[k].x += (v[k].x - mu) * rs * g4[k].x + b4[k].x;
      acc[k].y += (v[k].y - mu) * rs * g4[k].y + b4[k].y;
      acc[k].z += (v[k].z - mu) * rs * g4[k].z + b4[k].z;
      acc[k].w += (v[k].w - mu) * rs * g4[k].w + b4[k].w;
    }
  }
#pragma unroll
  for (int k = 0; k < 4; ++k)
    ((float4*)&part[w][0])[k * 64 + lane] = acc[k];
  __syncthreads();

  float4 s = ((const float4*)&part[0][0])[tid];
#pragma unroll
  for (int w2 = 1; w2 < 4; ++w2) {
    float4 t4 = ((const float4*)&part[0][0])[w2 * 256 + tid];
    s.x += t4.x; s.y += t4.y; s.z += t4.z; s.w += t4.w;
  }
  const float il = 0.5f / (float)len;
  float4 e = ((const float4*)(er + (size_t)b * 1024))[tid];
  const float o0 = 0.5f * e.x + s.x * il;
  const float o1 = 0.5f * e.y + s.y * il;
  const float o2 = 0.5f * e.z + s.z * il;
  const float o3 = 0.5f * e.w + s.w * il;
  float ss = o0 * o0 + o1 * o1 + o2 * o2 + o3 * o3;
#pragma unroll
  for (int o = 1; o < 64; o <<= 1) ss += __shfl_xor(ss, o);
  if (lane == 0) red[w] = ss;
  __syncthreads();
  ss = red[0] + red[1] + red[2] + red[3];
  const float nrm = 1.f / (sqrtf(ss) + 1e-8f);
  ((float4*)(out + (size_t)b * 1024))[tid] = make_float4(o0 * nrm, o1 * nrm, o2 * nrm, o3 * nrm);
}

// ---------------------------------------------------------------------------
extern "C" void kernel_launch(void* const* d_in, const int* in_sizes, int n_in,
                              void* d_out, int out_size, void* d_ws, size_t ws_size,
                              hipStream_t stream) {
  (void)in_sizes; (void)n_in; (void)out_size; (void)ws_size;
  const float* images = (const float*)d_in[0];
  const int*   lens   = (const int*)d_in[1];
  const float* fc1_w = (const float*)d_in[2];
  const float* fc1_b = (const float*)d_in[3];
  const float* bn_g  = (const float*)d_in[4];
  const float* bn_b  = (const float*)d_in[5];
  const float* bn_m  = (const float*)d_in[6];
  const float* bn_v  = (const float*)d_in[7];
  const float* fc2_w = (const float*)d_in[8];
  const float* fc2_b = (const float*)d_in[9];
  const float* in_w  = (const float*)d_in[10];
  const float* in_b  = (const float*)d_in[11];
  const float* out_w = (const float*)d_in[12];
  const float* out_b = (const float*)d_in[13];
  const float* ln1_g = (const float*)d_in[14];
  const float* ln1_b = (const float*)d_in[15];
  const float* ff1_w = (const float*)d_in[16];
  const float* ff1_b = (const float*)d_in[17];
  const float* ff2_w = (const float*)d_in[18];
  const float* ff2_b = (const float*)d_in[19];
  const float* ln2_g = (const float*)d_in[20];
  const float* ln2_b = (const float*)d_in[21];
  float* out = (float*)d_out;

  char* ws = (char*)d_ws;
  const size_t OFF_IMG16 = 0;                          // 67108864
  const size_t OFF_FC1W  = 67108864;                   // 2097152
  const size_t OFF_FC2W  = OFF_FC1W + 2097152;         // 1048576
  const size_t OFF_INW   = OFF_FC2W + 1048576;         // 6291456
  const size_t OFF_OUTW  = OFF_INW  + 6291456;         // 2097152
  const size_t OFF_FF1W  = OFF_OUTW + 2097152;         // 2097152
  const size_t OFF_FF2W  = OFF_FF1W + 2097152;         // 2097152
  const size_t OFF_H1    = OFF_FF2W + 2097152;         // 16777216
  const size_t OFF_EMB32 = OFF_H1 + 16777216;          // 67108864
  const size_t OFF_EMB16 = OFF_EMB32 + 67108864;       // 33554432
  const size_t OFF_QKV   = OFF_EMB16 + 33554432;       // 100663296
  const size_t OFF_CTX   = OFF_QKV + 100663296;        // 33554432
  const size_t OFF_ERES  = OFF_CTX + 33554432;         // 1048576

  short* img16  = (short*)(ws + OFF_IMG16);
  short* fc1w16 = (short*)(ws + OFF_FC1W);
  short* fc2w16 = (short*)(ws + OFF_FC2W);
  short* inw16  = (short*)(ws + OFF_INW);
  short* outw16 = (short*)(ws + OFF_OUTW);
  short* ff1w16 = (short*)(ws + OFF_FF1W);
  short* ff2w16 = (short*)(ws + OFF_FF2W);
  short* h1     = (short*)(ws + OFF_H1);
  float* emb32  = (float*)(ws + OFF_EMB32);
  short* emb16  = (short*)(ws + OFF_EMB16);
  short* qkv16  = (short*)(ws + OFF_QKV);
  short* ctx16  = (short*)(ws + OFF_CTX);
  float* embres = (float*)(ws + OFF_ERES);
  float* x1s = (float*)(ws + OFF_IMG16);   // pre-LN1   (img16 dead)
  float* x1  = emb32;                      // post-LN1 f32 (emb32 dead after out-proj)
  short* x1h = emb16;                      // post-LN1 bf16
  short* ffh = ctx16;                      // ffn hidden
  float* x2s = (float*)(ws + OFF_IMG16);   // pre-LN2   (x1s dead)

  const dim3 blk(256);
  const size_t SMEM = 131072;

  // converts
  cvt_kernel<<<2048, blk, 0, stream>>>(images, img16, 33554432 / 4);
  CvtArgs ca;
  ca.src[0] = fc1_w; ca.dst[0] = fc1w16; ca.n4[0] = 1048576 / 4;
  ca.src[1] = fc2_w; ca.dst[1] = fc2w16; ca.n4[1] = 524288 / 4;
  ca.src[2] = in_w;  ca.dst[2] = inw16;  ca.n4[2] = 3145728 / 4;
  ca.src[3] = out_w; ca.dst[3] = outw16; ca.n4[3] = 1048576 / 4;
  ca.src[4] = ff1_w; ca.dst[4] = ff1w16; ca.n4[4] = 1048576 / 4;
  ca.src[5] = ff2_w; ca.dst[5] = ff2w16; ca.n4[5] = 1048576 / 4;
  cvt6_kernel<<<1024, blk, 0, stream>>>(ca);

  // fc1 + BN + ReLU -> h1 (bf16)   [old 128x128 kernel: N=512]
  gemm_bt_h1<<<dim3(4, 128), blk, 0, stream>>>(
      img16, fc1w16, fc1_b, bn_g, bn_b, bn_m, bn_v, h1, 16384, 512, 2048);
  // fc2 -> emb (f32 + bf16) + fused top-2 pooling -> embres
  gemm256<EPI_EMB><<<dim3(4, 64), 512, SMEM, stream>>>(
      h1, fc2w16, fc2_b, nullptr, lens, embres, emb32, emb16, 16384, 1024, 512);
  // qkv projection
  gemm256<EPI_QKV><<<dim3(12, 64), 512, SMEM, stream>>>(
      emb16, inw16, in_b, nullptr, nullptr, nullptr, nullptr, qkv16, 16384, 3072, 1024);
  // attention
  attn_kernel<<<2048, blk, 0, stream>>>(qkv16, lens, ctx16);
  // out projection + residual(emb32) -> pre-LN1
  gemm256<EPI_RES><<<dim3(4, 64), 512, SMEM, stream>>>(
      ctx16, outw16, out_b, emb32, nullptr, nullptr, x1s, nullptr, 16384, 1024, 1024);
  ln_kernel<<<16384, blk, 0, stream>>>(x1s, ln1_g, ln1_b, x1, x1h);
  // ffn
  gemm256<EPI_FF1><<<dim3(4, 64), 512, SMEM, stream>>>(
      x1h, ff1w16, ff1_b, nullptr, nullptr, nullptr, nullptr, ffh, 16384, 1024, 1024);
  gemm256<EPI_RES><<<dim3(4, 64), 512, SMEM, stream>>>(
      ffh, ff2w16, ff2_b, x1, nullptr, nullptr, x2s, nullptr, 16384, 1024, 1024);
  // fused LN2 + avg-pool + mix + normalize
  ln2_final_kernel<<<256, blk, 0, stream>>>(x2s, ln2_g, ln2_b, embres, lens, out);
}

// Round 3
// 419.770 us; speedup vs baseline: 1.6460x; 1.1163x over previous
//
#include <hip/hip_runtime.h>
#include <stdint.h>
#include <stddef.h>

// ---------------------------------------------------------------------------
// EncoderImageAggr: bf16-MFMA pipeline for MI355X (gfx950)
// B=256 L=64 IMG_DIM=2048 D=1024 H=8 DH=128. All GEMMs are C = A @ W^T.
// Round 3: gemm256 -> 8-phase-style read-ahead schedule (ds_reads overlap
//          MFMA via pre-barrier issue + reg double-buffer; 2 barriers/tile;
//          counted vmcnt(4)/half-step). f32 emb/x1 buffers eliminated
//          (bf16 residuals).
// ---------------------------------------------------------------------------

typedef short s16x8 __attribute__((ext_vector_type(8)));
typedef short s16x4 __attribute__((ext_vector_type(4)));
typedef float f32x4 __attribute__((ext_vector_type(4)));

#define LN_EPSF 1e-5f
#define BN_EPSF 1e-5f

__device__ __forceinline__ short f2bf(float f) {
  union { float f; uint32_t u; } x; x.f = f;
  uint32_t r = x.u + 0x7fffu + ((x.u >> 16) & 1u);   // RNE
  return (short)(r >> 16);
}
__device__ __forceinline__ float bf2f(short s) {
  union { uint32_t u; float f; } x; x.u = ((uint32_t)(uint16_t)s) << 16;
  return x.f;
}

typedef const __attribute__((address_space(1))) short glb_s16_t;
typedef __attribute__((address_space(3))) short lds_s16_t;

__device__ __forceinline__ void stage16(const short* g, short* l) {
  __builtin_amdgcn_global_load_lds((glb_s16_t*)g, (lds_s16_t*)l, 16, 0, 0);
}

// involution swizzle for [256][32]-bf16 (64B-row) LDS half-slots:
// flips byte bits 4-5 with (untouched) bits 7-8 -> conflict-free (measured 0)
__device__ __forceinline__ int swz(int off) {
  return off ^ (((off >> 7) & 3) << 4);
}

enum { EPI_EMB = 1, EPI_QKV = 2, EPI_FF1 = 3, EPI_RES = 4 };

// ---------------------------------------------------------------------------
// fp32 -> bf16 converts
// ---------------------------------------------------------------------------
__global__ __launch_bounds__(256)
void cvt_kernel(const float* __restrict__ in, short* __restrict__ out, int n4) {
  const int stride = gridDim.x * 256;
  for (int i = blockIdx.x * 256 + threadIdx.x; i < n4; i += stride) {
    float4 v = ((const float4*)in)[i];
    s16x4 h; h[0] = f2bf(v.x); h[1] = f2bf(v.y); h[2] = f2bf(v.z); h[3] = f2bf(v.w);
    ((s16x4*)out)[i] = h;
  }
}

struct CvtArgs { const float* src[6]; short* dst[6]; int n4[6]; };

__global__ __launch_bounds__(256)
void cvt6_kernel(CvtArgs a) {
#pragma unroll
  for (int s = 0; s < 6; ++s) {
    const int n = a.n4[s];
    const float4* in = (const float4*)a.src[s];
    s16x4* outp = (s16x4*)a.dst[s];
    for (int i = blockIdx.x * 256 + threadIdx.x; i < n; i += gridDim.x * 256) {
      float4 v = in[i];
      s16x4 h; h[0] = f2bf(v.x); h[1] = f2bf(v.y); h[2] = f2bf(v.z); h[3] = f2bf(v.w);
      outp[i] = h;
    }
  }
}

// ---------------------------------------------------------------------------
// 256x256 pipelined GEMM, C = A(M,K) @ Bw(N,K)^T. 512 thr = 8 waves (2Mx4N),
// per-wave 128x64 output. Half-step = K-slice of 32. LDS ring: 4 half-slots
// of [256][32]bf16 (16KB) per matrix. Prefetch 3 half-steps ahead (4 loads/
// thread/half-step); one counted vmcnt + one s_barrier per half-step.
// Fragment regs double-buffered so every ds_read overlaps the previous MFMA
// cluster and the barrier wait.
// ---------------------------------------------------------------------------
template<int EPI>
__global__ __launch_bounds__(512, 2)
void gemm256(const short* __restrict__ A, const short* __restrict__ Bw,
             const float* __restrict__ bias, const short* __restrict__ res16,
             const int* __restrict__ lens, float* __restrict__ embres,
             float* __restrict__ out32, short* __restrict__ out16,
             int M, int N, int K) {
  extern __shared__ char smem[];                 // 131072 B: A slots, then B
  (void)M;
  const int tid  = threadIdx.x;
  const int lane = tid & 63;
  const int w    = tid >> 6;
  const int wr   = w >> 2;                       // 0..1
  const int wc   = w & 3;                        // 0..3
  const int lrow = lane & 15;
  const int cg   = lane >> 4;                    // 0..3
  const int NH   = K >> 5;                       // half-steps (K-slices of 32)
  const int gx   = gridDim.x;

  // T1: bijective XCD swizzle (nwg % 8 == 0 for all launches)
  int wg = blockIdx.y * gx + blockIdx.x;
  {
    const int cpx = (gx * gridDim.y) >> 3;
    wg = (wg & 7) * cpx + (wg >> 3);
  }
  const int m0 = (wg / gx) * 256;
  const int n0 = (wg % gx) * 256;

  // per-thread staging source offsets (bytes within matrix), j = 0,1
  const int ldb = K * 2;
  size_t gA[2], gB[2];
#pragma unroll
  for (int j = 0; j < 2; ++j) {
    const int p = tid * 16 + j * 8192;
    const int l = swz(p);
    const int row = l >> 6, colb = l & 63;
    gA[j] = (size_t)(m0 + row) * ldb + colb;
    gB[j] = (size_t)(n0 + row) * ldb + colb;
  }
  const char* Ab = (const char*)A;
  const char* Bb = (const char*)Bw;
  char* ldsA = smem;
  char* ldsB = smem + 65536;
  const int wofs = w * 1024;

  auto stageApart = [&](int i) {           // A half of half-step i (2 loads)
    const int rg = ((i & 3) << 14) + wofs;
    const int ko = i * 64;
    stage16((const short*)(Ab + gA[0] + ko), (short*)(ldsA + rg));
    stage16((const short*)(Ab + gA[1] + ko), (short*)(ldsA + rg + 8192));
  };
  auto stageBpart = [&](int i) {           // B half of half-step i (2 loads)
    const int rg = ((i & 3) << 14) + wofs;
    const int ko = i * 64;
    stage16((const short*)(Bb + gB[0] + ko), (short*)(ldsB + rg));
    stage16((const short*)(Bb + gB[1] + ko), (short*)(ldsB + rg + 8192));
  };

  // per-thread swizzled ds_read offsets (within a 16KB half-slot)
  int offA[8], offB[4];
#pragma unroll
  for (int mf = 0; mf < 8; ++mf)
    offA[mf] = swz((wr * 128 + mf * 16 + lrow) * 64 + cg * 16);
#pragma unroll
  for (int nf = 0; nf < 4; ++nf)
    offB[nf] = swz((wc * 64 + nf * 16 + lrow) * 64 + cg * 16);

  f32x4 acc[8][4] = {};

  // prologue: stage H0..H2 (12 loads), confirm H0, pre-read its fragments
  stageApart(0); stageBpart(0);
  stageApart(1); stageBpart(1);
  stageApart(2); stageBpart(2);
  asm volatile("s_waitcnt vmcnt(8)" ::: "memory");
  __builtin_amdgcn_s_barrier();
  __builtin_amdgcn_sched_barrier(0);
  s16x8 af_cur[4], bf_cur[4], af_nxt[4], bf_nxt[4], af2[4];
#pragma unroll
  for (int m = 0; m < 4; ++m) af_cur[m] = *(const s16x8*)(ldsA + offA[m]);
#pragma unroll
  for (int n = 0; n < 4; ++n) bf_cur[n] = *(const s16x8*)(ldsB + offB[n]);

  for (int i = 0; i < NH - 1; ++i) {
    const int si  = i & 3;
    const int si1 = (i + 1) & 3;
    const char* pA  = ldsA + (si  << 14);
    const char* pA1 = ldsA + (si1 << 14);
    const char* pB1 = ldsB + (si1 << 14);

    if (i + 2 < NH) { asm volatile("s_waitcnt vmcnt(4)" ::: "memory"); }
    else            { asm volatile("s_waitcnt vmcnt(0)" ::: "memory"); }
    __builtin_amdgcn_s_barrier();
    __builtin_amdgcn_sched_barrier(0);

    // ---- sub0: read ahead (af hi of Hi, bf of Hi+1), MFMA on af_cur ----
#pragma unroll
    for (int m = 0; m < 4; ++m) af_nxt[m] = *(const s16x8*)(pA + offA[m + 4]);
#pragma unroll
    for (int n = 0; n < 4; ++n) bf_nxt[n] = *(const s16x8*)(pB1 + offB[n]);
    if (i + 3 < NH) stageApart(i + 3);
    asm volatile("s_waitcnt lgkmcnt(8)" ::: "memory");
    __builtin_amdgcn_sched_barrier(0);
    __builtin_amdgcn_s_setprio(1);
#pragma unroll
    for (int m = 0; m < 4; ++m)
#pragma unroll
      for (int n = 0; n < 4; ++n)
        acc[m][n] = __builtin_amdgcn_mfma_f32_16x16x32_bf16(af_cur[m], bf_cur[n], acc[m][n], 0, 0, 0);
    __builtin_amdgcn_s_setprio(0);

    // ---- sub1: read ahead (af lo of Hi+1), MFMA on af_nxt ----
#pragma unroll
    for (int m = 0; m < 4; ++m) af2[m] = *(const s16x8*)(pA1 + offA[m]);
    if (i + 3 < NH) stageBpart(i + 3);
    asm volatile("s_waitcnt lgkmcnt(4)" ::: "memory");
    __builtin_amdgcn_sched_barrier(0);
    __builtin_amdgcn_s_setprio(1);
#pragma unroll
    for (int m = 0; m < 4; ++m)
#pragma unroll
      for (int n = 0; n < 4; ++n)
        acc[m + 4][n] = __builtin_amdgcn_mfma_f32_16x16x32_bf16(af_nxt[m], bf_cur[n], acc[m + 4][n], 0, 0, 0);
    __builtin_amdgcn_s_setprio(0);

#pragma unroll
    for (int m = 0; m < 4; ++m) af_cur[m] = af2[m];
#pragma unroll
    for (int n = 0; n < 4; ++n) bf_cur[n] = bf_nxt[n];
  }

  // ---- peeled last half-step ----
  {
    const char* pA = ldsA + (((NH - 1) & 3) << 14);
    asm volatile("s_waitcnt vmcnt(0)" ::: "memory");
    __builtin_amdgcn_s_barrier();
    __builtin_amdgcn_sched_barrier(0);
#pragma unroll
    for (int m = 0; m < 4; ++m) af_nxt[m] = *(const s16x8*)(pA + offA[m + 4]);
    asm volatile("s_waitcnt lgkmcnt(4)" ::: "memory");
    __builtin_amdgcn_sched_barrier(0);
    __builtin_amdgcn_s_setprio(1);
#pragma unroll
    for (int m = 0; m < 4; ++m)
#pragma unroll
      for (int n = 0; n < 4; ++n)
        acc[m][n] = __builtin_amdgcn_mfma_f32_16x16x32_bf16(af_cur[m], bf_cur[n], acc[m][n], 0, 0, 0);
    __builtin_amdgcn_s_setprio(0);
    asm volatile("s_waitcnt lgkmcnt(0)" ::: "memory");
    __builtin_amdgcn_sched_barrier(0);
    __builtin_amdgcn_s_setprio(1);
#pragma unroll
    for (int m = 0; m < 4; ++m)
#pragma unroll
      for (int n = 0; n < 4; ++n)
        acc[m + 4][n] = __builtin_amdgcn_mfma_f32_16x16x32_bf16(af_nxt[m], bf_cur[n], acc[m + 4][n], 0, 0, 0);
    __builtin_amdgcn_s_setprio(0);
  }

  // ---- epilogue (C/D layout: row=(lane>>4)*4+r, col=lane&15 per 16x16) ----
  const int ecol0 = n0 + wc * 64 + lrow;
  float bz[4];
#pragma unroll
  for (int nf = 0; nf < 4; ++nf) bz[nf] = bias[ecol0 + nf * 16];
  const int erow0 = m0 + wr * 128 + (cg << 2);

  float t1[2][4], t2[2][4];
  int len0 = 0, len1 = 0;
  if constexpr (EPI == EPI_EMB) {
    const int bat0 = (m0 >> 6) + wr * 2;
    len0 = lens[bat0]; len1 = lens[bat0 + 1];
#pragma unroll
    for (int g = 0; g < 2; ++g)
#pragma unroll
      for (int nf = 0; nf < 4; ++nf) { t1[g][nf] = -3.0e38f; t2[g][nf] = -3.0e38f; }
  }

#pragma unroll
  for (int mf = 0; mf < 8; ++mf) {
#pragma unroll
    for (int nf = 0; nf < 4; ++nf) {
#pragma unroll
      for (int r = 0; r < 4; ++r) {
        const int row = erow0 + mf * 16 + r;
        const size_t idx = (size_t)row * N + (ecol0 + nf * 16);
        const float v = acc[mf][nf][r] + bz[nf];
        if constexpr (EPI == EPI_EMB) {
          out16[idx] = f2bf(v);
          const int g = mf >> 2;
          const int token = (mf & 3) * 16 + (cg << 2) + r;
          const float vm = (token < (g ? len1 : len0)) ? v : -3.0e38f;
          float* a1 = &t1[g][nf];
          float* a2 = &t2[g][nf];
          if (vm > *a1) { *a2 = *a1; *a1 = vm; }
          else if (vm > *a2) { *a2 = vm; }
        } else if constexpr (EPI == EPI_QKV) {
          out16[idx] = f2bf(v);
        } else if constexpr (EPI == EPI_FF1) {
          out16[idx] = f2bf(fmaxf(v, 0.f));
        } else {  // EPI_RES: f32 out = v + bf16 residual
          out32[idx] = v + bf2f(res16[idx]);
        }
      }
    }
  }

  if constexpr (EPI == EPI_EMB) {
    const int bat0 = (m0 >> 6) + wr * 2;
#pragma unroll
    for (int g = 0; g < 2; ++g)
#pragma unroll
      for (int nf = 0; nf < 4; ++nf) {
        float a1 = t1[g][nf], a2 = t2[g][nf];
#pragma unroll
        for (int d = 16; d <= 32; d <<= 1) {
          const float b1 = __shfl_xor(a1, d);
          const float b2 = __shfl_xor(a2, d);
          const float n1 = fmaxf(a1, b1);
          const float n2 = fmaxf(fminf(a1, b1), fmaxf(a2, b2));
          a1 = n1; a2 = n2;
        }
        if (cg == 0)
          embres[(size_t)(bat0 + g) * 1024 + ecol0 + nf * 16] = 0.5f * (a1 + a2);
      }
  }
}

// ---------------------------------------------------------------------------
// 128x128 GEMM for fc1 (N=512 keeps 512 blocks; fused BN+ReLU epilogue)
// ---------------------------------------------------------------------------
__global__ __launch_bounds__(256)
void gemm_bt_h1(const short* __restrict__ A, const short* __restrict__ Bw,
                const float* __restrict__ bias,
                const float* __restrict__ bn_g, const float* __restrict__ bn_b,
                const float* __restrict__ bn_m, const float* __restrict__ bn_v,
                short* __restrict__ out16, int M, int N, int K) {
  __shared__ short As[128 * 32];
  __shared__ short Bs[128 * 32];
  (void)M;
  const int tid  = threadIdx.x;
  const int lane = tid & 63;
  const int wave = tid >> 6;
  const int m0 = blockIdx.y * 128;
  const int n0 = blockIdx.x * 128;
  const int wm = (wave >> 1) * 64;
  const int wn = (wave & 1) * 64;
  const int lrow = lane & 15;
  const int lk8  = (lane >> 4) * 8;

  f32x4 acc[4][4] = {};

  const int srow = wave * 16 + (lane >> 2);
  const int scol = (lane & 3) * 8;
  const short* gA = A  + (size_t)(m0 + srow) * K + scol;
  const short* gB = Bw + (size_t)(n0 + srow) * K + scol;
  short* lA = &As[(wave * 16) * 32];
  short* lB = &Bs[(wave * 16) * 32];
  const size_t half = (size_t)64 * K;

  for (int k0 = 0; k0 < K; k0 += 32) {
    stage16(gA + k0,        lA);
    stage16(gA + half + k0, lA + 64 * 32);
    stage16(gB + k0,        lB);
    stage16(gB + half + k0, lB + 64 * 32);
    __syncthreads();
    s16x8 af[4], bfr[4];
#pragma unroll
    for (int m = 0; m < 4; ++m)
      af[m] = *(const s16x8*)&As[(wm + m * 16 + lrow) * 32 + lk8];
#pragma unroll
    for (int n = 0; n < 4; ++n)
      bfr[n] = *(const s16x8*)&Bs[(wn + n * 16 + lrow) * 32 + lk8];
#pragma unroll
    for (int m = 0; m < 4; ++m)
#pragma unroll
      for (int n = 0; n < 4; ++n)
        acc[m][n] = __builtin_amdgcn_mfma_f32_16x16x32_bf16(af[m], bfr[n], acc[m][n], 0, 0, 0);
    __syncthreads();
  }

  const int erow = m0 + wm + ((lane >> 4) << 2);
  const int ecol = n0 + wn + lrow;
  float sc[4], sh[4];
#pragma unroll
  for (int n = 0; n < 4; ++n) {
    const int c = ecol + n * 16;
    const float s = bn_g[c] * rsqrtf(bn_v[c] + BN_EPSF);
    sc[n] = s;
    sh[n] = (bias[c] - bn_m[c]) * s + bn_b[c];
  }
#pragma unroll
  for (int m = 0; m < 4; ++m)
#pragma unroll
    for (int n = 0; n < 4; ++n)
#pragma unroll
      for (int r = 0; r < 4; ++r) {
        const size_t idx = (size_t)(erow + m * 16 + r) * N + (ecol + n * 16);
        out16[idx] = f2bf(fmaxf(acc[m][n][r] * sc[n] + sh[n], 0.f));
      }
}

// ---------------------------------------------------------------------------
// Fused attention: one block per (b,h). qkv is (B*L, 3072) bf16.
// ---------------------------------------------------------------------------
__global__ __launch_bounds__(256)
void attn_kernel(const short* __restrict__ qkv, const int* __restrict__ lens,
                 short* __restrict__ ctx) {
  __shared__ short Qs[64 * 128];
  __shared__ short Ks[64 * 128];
  __shared__ short Vt[128 * 64];
  const int tid  = threadIdx.x;
  const int lane = tid & 63;
  const int wave = tid >> 6;
  const int b = blockIdx.x >> 3;
  const int h = blockIdx.x & 7;
  const int len = lens[b];
  const size_t qb = (size_t)(b * 64) * 3072 + h * 128;

  {
    const int rr = wave * 4 + (lane >> 4);
    const int cc = (lane & 15) * 8;
#pragma unroll
    for (int r = 0; r < 4; ++r) {
      stage16(qkv + qb +        (size_t)(r * 16 + rr) * 3072 + cc, &Qs[(r * 16 + wave * 4) * 128]);
      stage16(qkv + qb + 1024 + (size_t)(r * 16 + rr) * 3072 + cc, &Ks[(r * 16 + wave * 4) * 128]);
    }
  }
#pragma unroll
  for (int i = 0; i < 2; ++i) {
    const int c  = i * 256 + tid;
    const int lp = c >> 4;
    const int dg = c & 15;
    const short* src = qkv + qb + 2048 + (size_t)(2 * lp) * 3072 + dg * 8;
    s16x8 v0 = *(const s16x8*)src;
    s16x8 v1 = *(const s16x8*)(src + 3072);
#pragma unroll
    for (int j = 0; j < 8; ++j) {
      uint32_t pk = ((uint32_t)(uint16_t)v0[j]) | (((uint32_t)(uint16_t)v1[j]) << 16);
      *(uint32_t*)&Vt[(dg * 8 + j) * 64 + 2 * lp] = pk;
    }
  }
  __syncthreads();

  const int lrow = lane & 15;
  const int lk8  = (lane >> 4) * 8;

  f32x4 sacc[4] = {};
#pragma unroll
  for (int ks = 0; ks < 4; ++ks) {
    s16x8 aq = *(const s16x8*)&Qs[(wave * 16 + lrow) * 128 + ks * 32 + lk8];
#pragma unroll
    for (int n = 0; n < 4; ++n) {
      s16x8 bk = *(const s16x8*)&Ks[(n * 16 + lrow) * 128 + ks * 32 + lk8];
      sacc[n] = __builtin_amdgcn_mfma_f32_16x16x32_bf16(aq, bk, sacc[n], 0, 0, 0);
    }
  }

  const float scale = 0.08838834764831845f;
#pragma unroll
  for (int r = 0; r < 4; ++r) {
    float sv[4];
    float mx = -1e30f;
#pragma unroll
    for (int n = 0; n < 4; ++n) {
      float v = sacc[n][r] * scale;
      if (n * 16 + lrow >= len) v = -1e30f;
      sv[n] = v;
      mx = fmaxf(mx, v);
    }
    mx = fmaxf(mx, __shfl_xor(mx, 1));
    mx = fmaxf(mx, __shfl_xor(mx, 2));
    mx = fmaxf(mx, __shfl_xor(mx, 4));
    mx = fmaxf(mx, __shfl_xor(mx, 8));
    float pv[4], sum = 0.f;
#pragma unroll
    for (int n = 0; n < 4; ++n) { pv[n] = __expf(sv[n] - mx); sum += pv[n]; }
    sum += __shfl_xor(sum, 1);
    sum += __shfl_xor(sum, 2);
    sum += __shfl_xor(sum, 4);
    sum += __shfl_xor(sum, 8);
    const float inv = 1.f / sum;
    const int prow = wave * 16 + ((lane >> 4) << 2) + r;
#pragma unroll
    for (int n = 0; n < 4; ++n)
      Qs[prow * 128 + n * 16 + lrow] = f2bf(pv[n] * inv);
  }
  __syncthreads();

  f32x4 oacc[8] = {};
#pragma unroll
  for (int ks = 0; ks < 2; ++ks) {
    s16x8 ap = *(const s16x8*)&Qs[(wave * 16 + lrow) * 128 + ks * 32 + lk8];
#pragma unroll
    for (int n = 0; n < 8; ++n) {
      s16x8 bv = *(const s16x8*)&Vt[(n * 16 + lrow) * 64 + ks * 32 + lk8];
      oacc[n] = __builtin_amdgcn_mfma_f32_16x16x32_bf16(ap, bv, oacc[n], 0, 0, 0);
    }
  }
  const size_t ob = (size_t)(b * 64) * 1024 + h * 128;
#pragma unroll
  for (int n = 0; n < 8; ++n)
#pragma unroll
    for (int r = 0; r < 4; ++r) {
      const int row = wave * 16 + ((lane >> 4) << 2) + r;
      ctx[ob + (size_t)row * 1024 + n * 16 + lrow] = f2bf(oacc[n][r]);
    }
}

// ---------------------------------------------------------------------------
// LayerNorm over 1024 (LN1), one block per row; writes bf16 only
// ---------------------------------------------------------------------------
__global__ __launch_bounds__(256)
void ln_kernel(const float* __restrict__ x, const float* __restrict__ gg,
               const float* __restrict__ bb, short* __restrict__ y16) {
  __shared__ float red[8];
  const int tid = threadIdx.x;
  const int lane = tid & 63;
  const int wave = tid >> 6;
  const size_t base = (size_t)blockIdx.x * 1024;
  float4 v = ((const float4*)(x + base))[tid];
  float s1 = v.x + v.y + v.z + v.w;
  float s2 = v.x * v.x + v.y * v.y + v.z * v.z + v.w * v.w;
#pragma unroll
  for (int o = 1; o < 64; o <<= 1) { s1 += __shfl_xor(s1, o); s2 += __shfl_xor(s2, o); }
  if (lane == 0) { red[wave] = s1; red[wave + 4] = s2; }
  __syncthreads();
  s1 = red[0] + red[1] + red[2] + red[3];
  s2 = red[4] + red[5] + red[6] + red[7];
  const float mu  = s1 * (1.f / 1024.f);
  const float var = fmaxf(s2 * (1.f / 1024.f) - mu * mu, 0.f);
  const float rs  = rsqrtf(var + LN_EPSF);
  float4 g4 = ((const float4*)gg)[tid];
  float4 b4 = ((const float4*)bb)[tid];
  s16x4 hh;
  hh[0] = f2bf((v.x - mu) * rs * g4.x + b4.x);
  hh[1] = f2bf((v.y - mu) * rs * g4.y + b4.y);
  hh[2] = f2bf((v.z - mu) * rs * g4.z + b4.z);
  hh[3] = f2bf((v.w - mu) * rs * g4.w + b4.w);
  ((s16x4*)(y16 + base))[tid] = hh;
}

// ---------------------------------------------------------------------------
// fused LN2 + avg-pool over valid tokens + 0.5/0.5 mix + L2 normalize.
// ---------------------------------------------------------------------------
__global__ __launch_bounds__(256)
void ln2_final_kernel(const float* __restrict__ x, const float* __restrict__ gg,
                      const float* __restrict__ bb, const float* __restrict__ er,
                      const int* __restrict__ lens, float* __restrict__ out) {
  __shared__ float part[4][1024];
  __shared__ float red[4];
  const int tid = threadIdx.x, lane = tid & 63, w = tid >> 6;
  const int b = blockIdx.x, len = lens[b];
  float4 g4[4], b4[4];
#pragma unroll
  for (int k = 0; k < 4; ++k) {
    g4[k] = ((const float4*)gg)[k * 64 + lane];
    b4[k] = ((const float4*)bb)[k * 64 + lane];
  }
  float4 acc[4];
#pragma unroll
  for (int k = 0; k < 4; ++k) acc[k] = make_float4(0.f, 0.f, 0.f, 0.f);

  for (int l = w; l < len; l += 4) {
    const float4* row = (const float4*)(x + ((size_t)b * 64 + l) * 1024);
    float4 v[4]; float s1 = 0.f, s2 = 0.f;
#pragma unroll
    for (int k = 0; k < 4; ++k) {
      v[k] = row[k * 64 + lane];
      s1 += v[k].x + v[k].y + v[k].z + v[k].w;
      s2 += v[k].x * v[k].x + v[k].y * v[k].y + v[k].z * v[k].z + v[k].w * v[k].w;
    }
#pragma unroll
    for (int o = 1; o < 64; o <<= 1) { s1 += __shfl_xor(s1, o); s2 += __shfl_xor(s2, o); }
    const float mu = s1 * (1.f / 1024.f);
    const float rs = rsqrtf(fmaxf(s2 * (1.f / 1024.f) - mu * mu, 0.f) + LN_EPSF);
#pragma unroll
    for (int k = 0; k < 4; ++k) {
      acc[k].x += (v[k].x - mu) * rs * g4[k].x + b4[k].x;
      acc[k].y += (v[k].y - mu) * rs * g4[k].y + b4[k].y;
      acc[k].z += (v[k].z - mu) * rs * g4[k].z + b4[k].z;
      acc[k].w += (v[k].w - mu) * rs * g4[k].w + b4[k].w;
    }
  }
#pragma unroll
  for (int k = 0; k < 4; ++k)
    ((float4*)&part[w][0])[k * 64 + lane] = acc[k];
  __syncthreads();

  float4 s = ((const float4*)&part[0][0])[tid];
#pragma unroll
  for (int w2 = 1; w2 < 4; ++w2) {
    float4 t4 = ((const float4*)&part[0][0])[w2 * 256 + tid];
    s.x += t4.x; s.y += t4.y; s.z += t4.z; s.w += t4.w;
  }
  const float il = 0.5f / (float)len;
  float4 e = ((const float4*)(er + (size_t)b * 1024))[tid];
  const float o0 = 0.5f * e.x + s.x * il;
  const float o1 = 0.5f * e.y + s.y * il;
  const float o2 = 0.5f * e.z + s.z * il;
  const float o3 = 0.5f * e.w + s.w * il;
  float ss = o0 * o0 + o1 * o1 + o2 * o2 + o3 * o3;
#pragma unroll
  for (int o = 1; o < 64; o <<= 1) ss += __shfl_xor(ss, o);
  if (lane == 0) red[w] = ss;
  __syncthreads();
  ss = red[0] + red[1] + red[2] + red[3];
  const float nrm = 1.f / (sqrtf(ss) + 1e-8f);
  ((float4*)(out + (size_t)b * 1024))[tid] = make_float4(o0 * nrm, o1 * nrm, o2 * nrm, o3 * nrm);
}

// ---------------------------------------------------------------------------
extern "C" void kernel_launch(void* const* d_in, const int* in_sizes, int n_in,
                              void* d_out, int out_size, void* d_ws, size_t ws_size,
                              hipStream_t stream) {
  (void)in_sizes; (void)n_in; (void)out_size; (void)ws_size;
  const float* images = (const float*)d_in[0];
  const int*   lens   = (const int*)d_in[1];
  const float* fc1_w = (const float*)d_in[2];
  const float* fc1_b = (const float*)d_in[3];
  const float* bn_g  = (const float*)d_in[4];
  const float* bn_b  = (const float*)d_in[5];
  const float* bn_m  = (const float*)d_in[6];
  const float* bn_v  = (const float*)d_in[7];
  const float* fc2_w = (const float*)d_in[8];
  const float* fc2_b = (const float*)d_in[9];
  const float* in_w  = (const float*)d_in[10];
  const float* in_b  = (const float*)d_in[11];
  const float* out_w = (const float*)d_in[12];
  const float* out_b = (const float*)d_in[13];
  const float* ln1_g = (const float*)d_in[14];
  const float* ln1_b = (const float*)d_in[15];
  const float* ff1_w = (const float*)d_in[16];
  const float* ff1_b = (const float*)d_in[17];
  const float* ff2_w = (const float*)d_in[18];
  const float* ff2_b = (const float*)d_in[19];
  const float* ln2_g = (const float*)d_in[20];
  const float* ln2_b = (const float*)d_in[21];
  float* out = (float*)d_out;

  char* ws = (char*)d_ws;
  const size_t OFF_IMG16 = 0;                          // 67108864 (img16 / x1s / x2s)
  const size_t OFF_FC1W  = 67108864;                   // 2097152
  const size_t OFF_FC2W  = OFF_FC1W + 2097152;         // 1048576
  const size_t OFF_INW   = OFF_FC2W + 1048576;         // 6291456
  const size_t OFF_OUTW  = OFF_INW  + 6291456;         // 2097152
  const size_t OFF_FF1W  = OFF_OUTW + 2097152;         // 2097152
  const size_t OFF_FF2W  = OFF_FF1W + 2097152;         // 2097152
  const size_t OFF_H1    = OFF_FF2W + 2097152;         // 16777216
  const size_t OFF_EMB16 = OFF_H1 + 16777216;          // 33554432
  const size_t OFF_QKV   = OFF_EMB16 + 33554432;       // 100663296
  const size_t OFF_CTX   = OFF_QKV + 100663296;        // 33554432
  const size_t OFF_ERES  = OFF_CTX + 33554432;         // 1048576

  short* img16  = (short*)(ws + OFF_IMG16);
  short* fc1w16 = (short*)(ws + OFF_FC1W);
  short* fc2w16 = (short*)(ws + OFF_FC2W);
  short* inw16  = (short*)(ws + OFF_INW);
  short* outw16 = (short*)(ws + OFF_OUTW);
  short* ff1w16 = (short*)(ws + OFF_FF1W);
  short* ff2w16 = (short*)(ws + OFF_FF2W);
  short* h1     = (short*)(ws + OFF_H1);
  short* emb16  = (short*)(ws + OFF_EMB16);
  short* qkv16  = (short*)(ws + OFF_QKV);
  short* ctx16  = (short*)(ws + OFF_CTX);
  float* embres = (float*)(ws + OFF_ERES);
  float* x1s = (float*)(ws + OFF_IMG16);   // pre-LN1 f32  (img16 dead)
  short* x1h = emb16;                      // post-LN1 bf16 (emb16 dead after out-proj)
  short* ffh = ctx16;                      // ffn hidden    (ctx16 dead)
  float* x2s = (float*)(ws + OFF_IMG16);   // pre-LN2 f32   (x1s dead)

  const dim3 blk(256);
  const size_t SMEM = 131072;

  // converts
  cvt_kernel<<<2048, blk, 0, stream>>>(images, img16, 33554432 / 4);
  CvtArgs ca;
  ca.src[0] = fc1_w; ca.dst[0] = fc1w16; ca.n4[0] = 1048576 / 4;
  ca.src[1] = fc2_w; ca.dst[1] = fc2w16; ca.n4[1] = 524288 / 4;
  ca.src[2] = in_w;  ca.dst[2] = inw16;  ca.n4[2] = 3145728 / 4;
  ca.src[3] = out_w; ca.dst[3] = outw16; ca.n4[3] = 1048576 / 4;
  ca.src[4] = ff1_w; ca.dst[4] = ff1w16; ca.n4[4] = 1048576 / 4;
  ca.src[5] = ff2_w; ca.dst[5] = ff2w16; ca.n4[5] = 1048576 / 4;
  cvt6_kernel<<<1024, blk, 0, stream>>>(ca);

  // fc1 + BN + ReLU -> h1 (bf16)
  gemm_bt_h1<<<dim3(4, 128), blk, 0, stream>>>(
      img16, fc1w16, fc1_b, bn_g, bn_b, bn_m, bn_v, h1, 16384, 512, 2048);
  // fc2 -> emb16 + fused top-2 pooling -> embres
  gemm256<EPI_EMB><<<dim3(4, 64), 512, SMEM, stream>>>(
      h1, fc2w16, fc2_b, nullptr, lens, embres, nullptr, emb16, 16384, 1024, 512);
  // qkv projection
  gemm256<EPI_QKV><<<dim3(12, 64), 512, SMEM, stream>>>(
      emb16, inw16, in_b, nullptr, nullptr, nullptr, nullptr, qkv16, 16384, 3072, 1024);
  // attention
  attn_kernel<<<2048, blk, 0, stream>>>(qkv16, lens, ctx16);
  // out projection + residual(emb16) -> pre-LN1 f32
  gemm256<EPI_RES><<<dim3(4, 64), 512, SMEM, stream>>>(
      ctx16, outw16, out_b, emb16, nullptr, nullptr, x1s, nullptr, 16384, 1024, 1024);
  ln_kernel<<<16384, blk, 0, stream>>>(x1s, ln1_g, ln1_b, x1h);
  // ffn
  gemm256<EPI_FF1><<<dim3(4, 64), 512, SMEM, stream>>>(
      x1h, ff1w16, ff1_b, nullptr, nullptr, nullptr, nullptr, ffh, 16384, 1024, 1024);
  gemm256<EPI_RES><<<dim3(4, 64), 512, SMEM, stream>>>(
      ffh, ff2w16, ff2_b, x1h, nullptr, nullptr, x2s, nullptr, 16384, 1024, 1024);
  // fused LN2 + avg-pool + mix + normalize
  ln2_final_kernel<<<256, blk, 0, stream>>>(x2s, ln2_g, ln2_b, embres, lens, out);
}